// Round 7
// baseline (255.445 us; speedup 1.0000x reference)
//
#include <hip/hip_runtime.h>
#include <stdint.h>

typedef unsigned short u16;
typedef unsigned int u32;
typedef short v8s __attribute__((ext_vector_type(8)));
typedef float v4f __attribute__((ext_vector_type(4)));

#define N_NODES 8192
#define N_EDGES 524288
#define DFEAT 256
#define PAD 160   // per-receiver bucket capacity; deg ~ Bin(524288, 2^-13): mean 64, sigma 8

static __device__ __forceinline__ float bflo(u32 u) { return __uint_as_float(u << 16); }
static __device__ __forceinline__ float bfhi(u32 u) { return __uint_as_float(u & 0xffff0000u); }
static __device__ __forceinline__ u16 f2bf(float f) {
    u32 u = __float_as_uint(f);
    u32 r = (u + 0x7fffu + ((u >> 16) & 1u)) >> 16;
    return (u16)r;
}

// ---- prep: padded-bucket scatter | LDS-tiled W transpose->bf16 ----
// grid: [0,2048) scatter, [2048,2096) transpose
__global__ void prep(const float* __restrict__ w0, const float* __restrict__ w1,
                     const float* __restrict__ w2,
                     const int* __restrict__ recv, const int* __restrict__ send,
                     u16* __restrict__ wt,
                     int* __restrict__ cnt, int* __restrict__ es_pad) {
    __shared__ u16 t[64][65];
    int b = blockIdx.x;
    if (b < 2048) {
        int e = b * 256 + threadIdx.x;
        int r = recv[e];
        int pos = atomicAdd(&cnt[r], 1);
        if (pos < PAD) es_pad[r * PAD + pos] = send[e];
    } else {
        int bb = b - 2048;
        int region = bb >> 4;
        int tile = bb & 15;
        int k0 = (tile >> 2) * 64, n0 = (tile & 3) * 64;
        const float* w = (region == 0) ? w0 : ((region == 1) ? w1 : w2);
        int tx = threadIdx.x & 63, ty = threadIdx.x >> 6;  // 64 x 4
#pragma unroll
        for (int it = 0; it < 16; it++) {
            int row = it * 4 + ty;
            t[row][tx] = f2bf(w[(k0 + row) * 256 + n0 + tx]);
        }
        __syncthreads();
        u16* o = wt + region * 65536;
#pragma unroll
        for (int it = 0; it < 16; it++) {
            int row = it * 4 + ty;
            o[(n0 + row) * 256 + k0 + tx] = t[tx][row];
        }
    }
}

// ---- bf16 MFMA GEMM reading f32 A directly, C = h @ {W|Wq|Wk} (+bias), out bf16 ----
__global__ __launch_bounds__(256) void gemm_proj(
    const float* __restrict__ h, const u16* __restrict__ wt,
    const float* __restrict__ bq, const float* __restrict__ bk,
    u16* __restrict__ hproj, u16* __restrict__ qb, u16* __restrict__ kb) {
    int wave = threadIdx.x >> 6;
    int lane = threadIdx.x & 63;
    int lm = lane & 15;
    int lq = lane >> 4;
    int m0 = blockIdx.x * 64 + wave * 16;
    int region = blockIdx.y >> 2;
    int n0b = (blockIdx.y & 3) * 64;
    const u16* wtr = wt + region * 65536;

    v4f acc[4];
#pragma unroll
    for (int nt = 0; nt < 4; nt++) acc[nt] = (v4f){0.f, 0.f, 0.f, 0.f};

    const float* arow = h + (m0 + lm) * 256 + lq * 8;
#pragma unroll
    for (int k0 = 0; k0 < 256; k0 += 32) {
        float4 u0 = *(const float4*)(arow + k0);
        float4 u1 = *(const float4*)(arow + k0 + 4);
        v8s a;
        a[0] = (short)f2bf(u0.x); a[1] = (short)f2bf(u0.y);
        a[2] = (short)f2bf(u0.z); a[3] = (short)f2bf(u0.w);
        a[4] = (short)f2bf(u1.x); a[5] = (short)f2bf(u1.y);
        a[6] = (short)f2bf(u1.z); a[7] = (short)f2bf(u1.w);
#pragma unroll
        for (int nt = 0; nt < 4; nt++) {
            v8s b = *(const v8s*)(wtr + (n0b + nt * 16 + lm) * 256 + k0 + lq * 8);
            acc[nt] = __builtin_amdgcn_mfma_f32_16x16x32_bf16(a, b, acc[nt], 0, 0, 0);
        }
    }

    u16* outp = (region == 0) ? hproj : ((region == 1) ? qb : kb);
    const float* bias = (region == 1) ? bq : ((region == 2) ? bk : nullptr);
#pragma unroll
    for (int nt = 0; nt < 4; nt++) {
        int n = n0b + nt * 16 + lm;
        float bv = bias ? bias[n] : 0.f;
#pragma unroll
        for (int i = 0; i < 4; i++) {
            int m = m0 + lq * 4 + i;
            outp[m * 256 + n] = f2bf(acc[nt][i] + bv);
        }
    }
}

// ---- fused edge kernel: 2 waves per receiver (even/odd tiles), VGPR gathers,
//      all 16 row-gathers issued BEFORE the score MFMA chain (h-latency overlaps MFMA) ----
__global__ __launch_bounds__(256) void edge_fused(
    const u16* __restrict__ qb, const u16* __restrict__ kb, const u16* __restrict__ hpb,
    const int* __restrict__ cnt, const int* __restrict__ es_pad,
    float* __restrict__ out) {
    __shared__ float sc[4][16];
    __shared__ float comb[2][64][8];
    int wave = threadIdx.x >> 6;
    int lane = threadIdx.x & 63;
    int rl = wave >> 1, part = wave & 1;
    int r = blockIdx.x * 2 + rl;
    int lm = lane & 15, lq = lane >> 4;
    int lh = lane & 31, half = lane >> 5;
    int n = min(cnt[r], PAD);
    int base = r * PAD;

    // hoist k_r fragments (B operand: same for all 16 cols)
    v8s kf[8];
    const u16* krow = kb + r * 256 + lq * 8;
#pragma unroll
    for (int t = 0; t < 8; t++) kf[t] = *(const v8s*)(krow + t * 32);

    float a[8];
#pragma unroll
    for (int i = 0; i < 8; i++) a[i] = 0.f;

    for (int c0 = part * 16; c0 < n; c0 += 32) {
        int jq = c0 + lm;
        if (jq >= n) jq = n - 1;                   // tail clamp (dups never aggregated)
        int sq = es_pad[base + jq];

        // issue ALL gathers for this tile up front: 8 q-fragments + 8 h-row-pairs
        const u16* qrow = qb + (long)sq * 256 + lq * 8;
        v8s qf[8];
#pragma unroll
        for (int t = 0; t < 8; t++) qf[t] = *(const v8s*)(qrow + t * 32);
        uint4 hv[8];
#pragma unroll
        for (int u = 0; u < 8; u++) {
            int sh = __shfl(sq, 2 * u + half, 64); // edge 2u+half's sender
            hv[u] = *(const uint4*)(hpb + (long)sh * 256 + lh * 8);
        }

        // scores while h-gathers are in flight
        v4f acc = (v4f){0.f, 0.f, 0.f, 0.f};
#pragma unroll
        for (int t = 0; t < 8; t++)
            acc = __builtin_amdgcn_mfma_f32_16x16x32_bf16(qf[t], kf[t], acc, 0, 0, 0);
        if (lm == 0) {                             // col 0 lanes hold rows lq*4 + 0..3
#pragma unroll
            for (int i = 0; i < 4; i++) sc[wave][lq * 4 + i] = acc[i];
        }
        __threadfence_block();                     // same-wave DS order

        int m = n - c0; if (m > 16) m = 16;
        if (m >= 16) {
#pragma unroll
            for (int u = 0; u < 8; u++) {
                float p = sc[wave][2 * u + half];
                uint4 hu = hv[u];
                a[0] += p * bflo(hu.x); a[1] += p * bfhi(hu.x);
                a[2] += p * bflo(hu.y); a[3] += p * bfhi(hu.y);
                a[4] += p * bflo(hu.z); a[5] += p * bfhi(hu.z);
                a[6] += p * bflo(hu.w); a[7] += p * bfhi(hu.w);
            }
        } else {
            for (int t = half; t < m; t += 2) {
                float p = sc[wave][t];
                uint4 hu = hv[t >> 1];
                a[0] += p * bflo(hu.x); a[1] += p * bfhi(hu.x);
                a[2] += p * bflo(hu.y); a[3] += p * bfhi(hu.y);
                a[4] += p * bflo(hu.z); a[5] += p * bfhi(hu.z);
                a[6] += p * bflo(hu.w); a[7] += p * bfhi(hu.w);
            }
        }
    }

    // combine the two partner waves, then the two halves
    if (part == 1) {
#pragma unroll
        for (int i = 0; i < 8; i++) comb[rl][lane][i] = a[i];
    }
    __syncthreads();
    if (part == 0) {
#pragma unroll
        for (int i = 0; i < 8; i++) a[i] += comb[rl][lane][i];
#pragma unroll
        for (int i = 0; i < 8; i++) a[i] += __shfl_xor(a[i], 32, 64);
        if (half == 0) {
            float4 o0, o1;
            o0.x = fmaxf(a[0], 0.f); o0.y = fmaxf(a[1], 0.f);
            o0.z = fmaxf(a[2], 0.f); o0.w = fmaxf(a[3], 0.f);
            o1.x = fmaxf(a[4], 0.f); o1.y = fmaxf(a[5], 0.f);
            o1.z = fmaxf(a[6], 0.f); o1.w = fmaxf(a[7], 0.f);
            float* op = out + r * 256 + lh * 8;
            *(float4*)op = o0;
            *(float4*)(op + 4) = o1;
        }
    }
}

extern "C" void kernel_launch(void* const* d_in, const int* in_sizes, int n_in,
                              void* d_out, int out_size, void* d_ws, size_t ws_size,
                              hipStream_t stream) {
    const float* h  = (const float*)d_in[0];
    const float* W  = (const float*)d_in[1];
    const float* Wq = (const float*)d_in[2];
    const float* bq = (const float*)d_in[3];
    const float* Wk = (const float*)d_in[4];
    const float* bk = (const float*)d_in[5];
    const int* senders   = (const int*)d_in[6];
    const int* receivers = (const int*)d_in[7];
    float* out = (float*)d_out;

    char* ws = (char*)d_ws;
    u16* wt     = (u16*)ws;                          // 384 KB
    u16* hproj  = (u16*)(ws + 393216);               // 4 MB
    u16* qb     = hproj + N_NODES * DFEAT;           // 4 MB
    u16* kb     = qb + N_NODES * DFEAT;              // 4 MB
    int* cnt    = (int*)(kb + N_NODES * DFEAT);      // 32 KB
    int* es_pad = cnt + N_NODES;                     // 8192*160*4 = 5.25 MB

    hipMemsetAsync(cnt, 0, N_NODES * sizeof(int), stream);
    prep<<<2096, 256, 0, stream>>>(W, Wq, Wk, receivers, senders, wt, cnt, es_pad);
    gemm_proj<<<dim3(128, 12), 256, 0, stream>>>(h, wt, bq, bk, hproj, qb, kb);
    edge_fused<<<N_NODES / 2, 256, 0, stream>>>(qb, kb, hproj, cnt, es_pad, out);
}

// Round 8
// 184.426 us; speedup vs baseline: 1.3851x; 1.3851x over previous
//
#include <hip/hip_runtime.h>
#include <stdint.h>

typedef unsigned short u16;
typedef unsigned int u32;
typedef short v8s __attribute__((ext_vector_type(8)));
typedef float v4f __attribute__((ext_vector_type(4)));

#define N_NODES 8192
#define N_EDGES 524288
#define DFEAT 256
#define PAD 160   // per-receiver bucket capacity; deg ~ Bin(524288, 2^-13): mean 64, sigma 8

static __device__ __forceinline__ float bflo(u32 u) { return __uint_as_float(u << 16); }
static __device__ __forceinline__ float bfhi(u32 u) { return __uint_as_float(u & 0xffff0000u); }
static __device__ __forceinline__ u16 f2bf(float f) {
    u32 u = __float_as_uint(f);
    u32 r = (u + 0x7fffu + ((u >> 16) & 1u)) >> 16;
    return (u16)r;
}

// ---- prep: padded-bucket scatter | LDS-tiled W transpose->bf16 ----
// grid: [0,2048) scatter, [2048,2096) transpose
__global__ void prep(const float* __restrict__ w0, const float* __restrict__ w1,
                     const float* __restrict__ w2,
                     const int* __restrict__ recv, const int* __restrict__ send,
                     u16* __restrict__ wt,
                     int* __restrict__ cnt, int* __restrict__ es_pad) {
    __shared__ u16 t[64][65];
    int b = blockIdx.x;
    if (b < 2048) {
        int e = b * 256 + threadIdx.x;
        int r = recv[e];
        int pos = atomicAdd(&cnt[r], 1);
        if (pos < PAD) es_pad[r * PAD + pos] = send[e];
    } else {
        int bb = b - 2048;
        int region = bb >> 4;
        int tile = bb & 15;
        int k0 = (tile >> 2) * 64, n0 = (tile & 3) * 64;
        const float* w = (region == 0) ? w0 : ((region == 1) ? w1 : w2);
        int tx = threadIdx.x & 63, ty = threadIdx.x >> 6;  // 64 x 4
#pragma unroll
        for (int it = 0; it < 16; it++) {
            int row = it * 4 + ty;
            t[row][tx] = f2bf(w[(k0 + row) * 256 + n0 + tx]);
        }
        __syncthreads();
        u16* o = wt + region * 65536;
#pragma unroll
        for (int it = 0; it < 16; it++) {
            int row = it * 4 + ty;
            o[(n0 + row) * 256 + k0 + tx] = t[tx][row];
        }
    }
}

// ---- bf16 MFMA GEMM reading f32 A directly, C = h @ {W|Wq|Wk} (+bias), out bf16 ----
__global__ __launch_bounds__(256) void gemm_proj(
    const float* __restrict__ h, const u16* __restrict__ wt,
    const float* __restrict__ bq, const float* __restrict__ bk,
    u16* __restrict__ hproj, u16* __restrict__ qb, u16* __restrict__ kb) {
    int wave = threadIdx.x >> 6;
    int lane = threadIdx.x & 63;
    int lm = lane & 15;
    int lq = lane >> 4;
    int m0 = blockIdx.x * 64 + wave * 16;
    int region = blockIdx.y >> 2;
    int n0b = (blockIdx.y & 3) * 64;
    const u16* wtr = wt + region * 65536;

    v4f acc[4];
#pragma unroll
    for (int nt = 0; nt < 4; nt++) acc[nt] = (v4f){0.f, 0.f, 0.f, 0.f};

    const float* arow = h + (m0 + lm) * 256 + lq * 8;
#pragma unroll
    for (int k0 = 0; k0 < 256; k0 += 32) {
        float4 u0 = *(const float4*)(arow + k0);
        float4 u1 = *(const float4*)(arow + k0 + 4);
        v8s a;
        a[0] = (short)f2bf(u0.x); a[1] = (short)f2bf(u0.y);
        a[2] = (short)f2bf(u0.z); a[3] = (short)f2bf(u0.w);
        a[4] = (short)f2bf(u1.x); a[5] = (short)f2bf(u1.y);
        a[6] = (short)f2bf(u1.z); a[7] = (short)f2bf(u1.w);
#pragma unroll
        for (int nt = 0; nt < 4; nt++) {
            v8s b = *(const v8s*)(wtr + (n0b + nt * 16 + lm) * 256 + k0 + lq * 8);
            acc[nt] = __builtin_amdgcn_mfma_f32_16x16x32_bf16(a, b, acc[nt], 0, 0, 0);
        }
    }

    u16* outp = (region == 0) ? hproj : ((region == 1) ? qb : kb);
    const float* bias = (region == 1) ? bq : ((region == 2) ? bk : nullptr);
#pragma unroll
    for (int nt = 0; nt < 4; nt++) {
        int n = n0b + nt * 16 + lm;
        float bv = bias ? bias[n] : 0.f;
#pragma unroll
        for (int i = 0; i < 4; i++) {
            int m = m0 + lq * 4 + i;
            outp[m * 256 + n] = f2bf(acc[nt][i] + bv);
        }
    }
}

// ---- fused edge kernel: ONE WAVE = ONE BLOCK = ONE RECEIVER (fine-grained backfill) ----
// Per 16-edge tile: q gather -> MFMA scores (B = k_r broadcast) -> 64B LDS relay ->
// half-wave-per-edge uint4 h gathers + weighted FMA. VGPR budget kept at R5's 64.
__global__ __launch_bounds__(64) void edge_fused(
    const u16* __restrict__ qb, const u16* __restrict__ kb, const u16* __restrict__ hpb,
    const int* __restrict__ cnt, const int* __restrict__ es_pad,
    float* __restrict__ out) {
    __shared__ float sc[16];
    int lane = threadIdx.x;
    int r = blockIdx.x;
    int lm = lane & 15, lq = lane >> 4;
    int lh = lane & 31, half = lane >> 5;
    int n = min(cnt[r], PAD);
    int base = r * PAD;

    // hoist k_r fragments (B operand: same for all 16 cols)
    v8s kf[8];
    const u16* krow = kb + r * 256 + lq * 8;
#pragma unroll
    for (int t = 0; t < 8; t++) kf[t] = *(const v8s*)(krow + t * 32);

    float a[8];
#pragma unroll
    for (int i = 0; i < 8; i++) a[i] = 0.f;

    for (int c0 = 0; c0 < n; c0 += 16) {
        int jq = c0 + lm;
        if (jq >= n) jq = n - 1;               // tail clamp (dup scores never aggregated)
        int sq = es_pad[base + jq];
        const u16* qrow = qb + (long)sq * 256 + lq * 8;
        v4f acc = (v4f){0.f, 0.f, 0.f, 0.f};
#pragma unroll
        for (int t = 0; t < 8; t++) {
            v8s av = *(const v8s*)(qrow + t * 32);
            acc = __builtin_amdgcn_mfma_f32_16x16x32_bf16(av, kf[t], acc, 0, 0, 0);
        }
        if (lm == 0) {                          // col 0 lanes hold rows lq*4 + 0..3
#pragma unroll
            for (int i = 0; i < 4; i++) sc[lq * 4 + i] = acc[i];
        }
        __threadfence_block();                  // same-wave DS write -> read ordering

        int m = n - c0;
        if (m >= 16) {
#pragma unroll
            for (int u = 0; u < 8; u++) {
                int sh = __shfl(sq, 2 * u + half, 64);
                float p = sc[2 * u + half];
                uint4 hu = *(const uint4*)(hpb + (long)sh * 256 + lh * 8);
                a[0] += p * bflo(hu.x); a[1] += p * bfhi(hu.x);
                a[2] += p * bflo(hu.y); a[3] += p * bfhi(hu.y);
                a[4] += p * bflo(hu.z); a[5] += p * bfhi(hu.z);
                a[6] += p * bflo(hu.w); a[7] += p * bfhi(hu.w);
            }
        } else {
            for (int t = half; t < m; t += 2) {
                int sh = __shfl(sq, t, 64);
                float p = sc[t];
                uint4 hu = *(const uint4*)(hpb + (long)sh * 256 + lh * 8);
                a[0] += p * bflo(hu.x); a[1] += p * bfhi(hu.x);
                a[2] += p * bflo(hu.y); a[3] += p * bfhi(hu.y);
                a[4] += p * bflo(hu.z); a[5] += p * bfhi(hu.z);
                a[6] += p * bflo(hu.w); a[7] += p * bfhi(hu.w);
            }
        }
    }

    // combine the two halves (alternating edges, same columns)
#pragma unroll
    for (int i = 0; i < 8; i++) a[i] += __shfl_xor(a[i], 32, 64);

    if (half == 0) {
        float4 o0, o1;
        o0.x = fmaxf(a[0], 0.f); o0.y = fmaxf(a[1], 0.f);
        o0.z = fmaxf(a[2], 0.f); o0.w = fmaxf(a[3], 0.f);
        o1.x = fmaxf(a[4], 0.f); o1.y = fmaxf(a[5], 0.f);
        o1.z = fmaxf(a[6], 0.f); o1.w = fmaxf(a[7], 0.f);
        float* op = out + r * 256 + lh * 8;
        *(float4*)op = o0;
        *(float4*)(op + 4) = o1;
    }
}

extern "C" void kernel_launch(void* const* d_in, const int* in_sizes, int n_in,
                              void* d_out, int out_size, void* d_ws, size_t ws_size,
                              hipStream_t stream) {
    const float* h  = (const float*)d_in[0];
    const float* W  = (const float*)d_in[1];
    const float* Wq = (const float*)d_in[2];
    const float* bq = (const float*)d_in[3];
    const float* Wk = (const float*)d_in[4];
    const float* bk = (const float*)d_in[5];
    const int* senders   = (const int*)d_in[6];
    const int* receivers = (const int*)d_in[7];
    float* out = (float*)d_out;

    char* ws = (char*)d_ws;
    u16* wt     = (u16*)ws;                          // 384 KB
    u16* hproj  = (u16*)(ws + 393216);               // 4 MB
    u16* qb     = hproj + N_NODES * DFEAT;           // 4 MB
    u16* kb     = qb + N_NODES * DFEAT;              // 4 MB
    int* cnt    = (int*)(kb + N_NODES * DFEAT);      // 32 KB
    int* es_pad = cnt + N_NODES;                     // 8192*160*4 = 5.25 MB

    hipMemsetAsync(cnt, 0, N_NODES * sizeof(int), stream);
    prep<<<2096, 256, 0, stream>>>(W, Wq, Wk, receivers, senders, wt, cnt, es_pad);
    gemm_proj<<<dim3(128, 12), 256, 0, stream>>>(h, wt, bq, bk, hproj, qb, kb);
    edge_fused<<<N_NODES, 64, 0, stream>>>(qb, kb, hproj, cnt, es_pad, out);
}